// Round 5
// baseline (566.936 us; speedup 1.0000x reference)
//
#include <hip/hip_runtime.h>

#define NPTS    131072     // 32 * 64 * 64 points
#define KC      1024       // codes
#define DD      64         // embedding dim
#define HWSZ    4096       // h*w
#define MARGINF 6e-5f      // packed-domain gap below which we refine on the f32 grid

typedef __attribute__((ext_vector_type(8))) short short8;  // 8 bf16 = 4 VGPRs
typedef __attribute__((ext_vector_type(4))) float f32x4;   // MFMA C/D frag

__device__ __forceinline__ ushort bf16_rne(float x) {
    unsigned u = __float_as_uint(x);
    unsigned r = u + 0x7fffu + ((u >> 16) & 1u);
    return (ushort)(r >> 16);
}

// numpy pairwise sum of a[d]^2, n=64 contiguous path: squares round separately,
// 8 accumulators in numpy's exact order. fp contract OFF (no fma fusion).
__device__ __forceinline__ float np_pairwise64_sq(const float* a) {
#pragma clang fp contract(off)
    float r0 = a[0] * a[0], r1 = a[1] * a[1], r2 = a[2] * a[2], r3 = a[3] * a[3];
    float r4 = a[4] * a[4], r5 = a[5] * a[5], r6 = a[6] * a[6], r7 = a[7] * a[7];
    for (int i = 8; i < 64; i += 8) {
        r0 += a[i + 0] * a[i + 0]; r1 += a[i + 1] * a[i + 1];
        r2 += a[i + 2] * a[i + 2]; r3 += a[i + 3] * a[i + 3];
        r4 += a[i + 4] * a[i + 4]; r5 += a[i + 5] * a[i + 5];
        r6 += a[i + 6] * a[i + 6]; r7 += a[i + 7] * a[i + 7];
    }
    return ((r0 + r1) + (r2 + r3)) + ((r4 + r5) + (r6 + r7));
}

// ---- E prep: LDS-staged; numpy-order ||e||^2; MFMA-fragment-ordered bf16 ---
// Ebuf block for (tile,kh,hl): element = E[tile*16+(lane&15)][kh*32+(lane>>4)*8+j]
__global__ void __launch_bounds__(256)
vq_prep_e(const float* __restrict__ emb, float* __restrict__ se32,
          float* __restrict__ sebB, ushort* __restrict__ Ebuf) {
    __shared__ float es_[64][65];
    const int tid = threadIdx.x;
    const int k0  = blockIdx.x * 64;
#pragma unroll
    for (int it = 0; it < 16; ++it) {
        int f = tid + it * 256;
        int kk = f >> 6, d = f & 63;
        es_[kk][d] = emb[(size_t)(k0 + kk) * DD + d];   // coalesced over d
    }
    __syncthreads();
    if (tid < 64) {
        float s = np_pairwise64_sq(&es_[tid][0]);
        se32[k0 + tid] = s;
        sebB[k0 + tid] = s + 0.5f;       // bias keeps scan scores strictly positive
    }
#pragma unroll
    for (int it = 0; it < 16; ++it) {
        int f = tid + it * 256;
        int kk = f >> 6, d = f & 63;
        int k = k0 + kk;
        int tile = k >> 4, colk = k & 15;
        int kh = d >> 5, quad = (d & 31) >> 3, jj = d & 7;
        float ev = es_[kk][d];
        ushort hb = bf16_rne(ev);
        float  hf = __uint_as_float(((unsigned)hb) << 16);
        int pos = (quad * 16 + colk) * 8 + jj;
        Ebuf[((tile * 2 + kh) * 2 + 0) * 512 + pos] = hb;
        Ebuf[((tile * 2 + kh) * 2 + 1) * 512 + pos] = bf16_rne(ev - hf);
    }
}

// ---- fused: stage x -> A frags -> MFMA scan (packed-uint argmin) -> outputs
__global__ void __launch_bounds__(256)
vq_main(const float* __restrict__ in, const float* __restrict__ emb,
        const ushort* __restrict__ Ebuf, const float* __restrict__ sebB,
        float* __restrict__ outq, float* __restrict__ outl, float* __restrict__ outi,
        int* __restrict__ cnt, int* __restrict__ queue) {
    __shared__ float xs[64][129];   // [c][j] (33 KB); later overwritten with outq values
    __shared__ int   sidx[128];
    const int tid = threadIdx.x;
    const int n0  = blockIdx.x * 128;     // 128 consecutive points, single batch image
    const int b   = n0 >> 12;
    const int hw0 = n0 & 4095;
    const float* inb = in + (size_t)b * DD * HWSZ;

    // stage exact x for the block's 128 points (coalesced over hw)
#pragma unroll
    for (int it = 0; it < 32; ++it) {
        int f = tid + it * 256;
        int c = f >> 7, j = f & 127;
        xs[c][j] = inb[c * HWSZ + hw0 + j];
    }
    __syncthreads();

    const int lane = tid & 63, wave = tid >> 6;
    const int quad = lane >> 4, col = lane & 15;

    // A fragments (bf16 hi/lo) straight from LDS
    short8 A[2][2][2];   // [psub][khalf][hi/lo]
#pragma unroll
    for (int p = 0; p < 2; ++p) {
        int pt = wave * 32 + p * 16 + col;
#pragma unroll
        for (int kh = 0; kh < 2; ++kh) {
            short8 ah, al;
#pragma unroll
            for (int j = 0; j < 8; ++j) {
                float xv = xs[kh * 32 + quad * 8 + j][pt];
                ushort hb = bf16_rne(xv);
                float  hf = __uint_as_float(((unsigned)hb) << 16);
                ah[j] = (short)hb;
                al[j] = (short)bf16_rne(xv - hf);
            }
            A[p][kh][0] = ah; A[p][kh][1] = al;
        }
    }

    unsigned b1[8], b2[8];          // packed: (score+0.5 bits & ~63) | tile
#pragma unroll
    for (int s = 0; s < 8; ++s) { b1[s] = 0xFFFFFFFFu; b2[s] = 0xFFFFFFFFu; }

    for (int g = 0; g < 16; ++g) {            // 64 codes per iteration
        short8 B[4][2][2];
        float  sB[4];
#pragma unroll
        for (int s = 0; s < 4; ++s) {
            int tile = g * 4 + s;
            sB[s] = sebB[tile * 16 + col];
#pragma unroll
            for (int kh = 0; kh < 2; ++kh)
#pragma unroll
                for (int hl = 0; hl < 2; ++hl)
                    B[s][kh][hl] = *(const short8*)(Ebuf + ((tile * 2 + kh) * 2 + hl) * 512 + lane * 8);
        }
        f32x4 acc[2][4];
#pragma unroll
        for (int p = 0; p < 2; ++p)
#pragma unroll
            for (int s = 0; s < 4; ++s) acc[p][s] = (f32x4){0.f, 0.f, 0.f, 0.f};
#pragma unroll
        for (int p = 0; p < 2; ++p)
#pragma unroll
            for (int s = 0; s < 4; ++s) {
                acc[p][s] = __builtin_amdgcn_mfma_f32_16x16x32_bf16(A[p][0][0], B[s][0][0], acc[p][s], 0, 0, 0);
                acc[p][s] = __builtin_amdgcn_mfma_f32_16x16x32_bf16(A[p][1][0], B[s][1][0], acc[p][s], 0, 0, 0);
                acc[p][s] = __builtin_amdgcn_mfma_f32_16x16x32_bf16(A[p][0][0], B[s][0][1], acc[p][s], 0, 0, 0);
                acc[p][s] = __builtin_amdgcn_mfma_f32_16x16x32_bf16(A[p][1][0], B[s][1][1], acc[p][s], 0, 0, 0);
                acc[p][s] = __builtin_amdgcn_mfma_f32_16x16x32_bf16(A[p][0][1], B[s][0][0], acc[p][s], 0, 0, 0);
                acc[p][s] = __builtin_amdgcn_mfma_f32_16x16x32_bf16(A[p][1][1], B[s][1][0], acc[p][s], 0, 0, 0);
            }
        // packed-uint fold: 4 codes per slot via sorted-2-of-4 insertion
#pragma unroll
        for (int p = 0; p < 2; ++p)
#pragma unroll
            for (int r = 0; r < 4; ++r) {
                unsigned q[4];
#pragma unroll
                for (int s = 0; s < 4; ++s) {
                    float t = fmaf(-2.f, acc[p][s][r], sB[s]);       // 0.5 + se - 2x.e > 0
                    q[s] = (__float_as_uint(t) & 0xFFFFFFC0u) | (unsigned)(g * 4 + s);
                }
                unsigned a  = min(q[0], q[1]), bb = max(q[0], q[1]);
                unsigned c2 = min(q[2], q[3]), d2 = max(q[2], q[3]);
                unsigned lo = min(a, c2), hi = max(a, c2);
                unsigned sec = min(min(bb, d2), hi);                  // 2nd smallest of 4
                int sl = p * 4 + r;
                b2[sl] = min(min(b2[sl], sec), max(b1[sl], lo));
                b1[sl] = min(b1[sl], lo);
            }
    }

    // decode + 16-col butterfly merge (first-index tie-break)
    unsigned v1[8], v2[8]; int ci[8];
#pragma unroll
    for (int s = 0; s < 8; ++s) {
        ci[s] = (int)(b1[s] & 63u) * 16 + col;
        v1[s] = b1[s] & 0xFFFFFFC0u;
        v2[s] = b2[s] & 0xFFFFFFC0u;
    }
#pragma unroll
    for (int off = 1; off < 16; off <<= 1) {
#pragma unroll
        for (int s = 0; s < 8; ++s) {
            unsigned o1 = (unsigned)__shfl_xor((int)v1[s], off);
            unsigned o2 = (unsigned)__shfl_xor((int)v2[s], off);
            int      oi = __shfl_xor(ci[s], off);
            unsigned nb2 = min(min(v2[s], o2), max(v1[s], o1));
            bool take = (o1 < v1[s]) || (o1 == v1[s] && oi < ci[s]);
            v1[s] = take ? o1 : v1[s];
            ci[s] = take ? oi : ci[s];
            v2[s] = nb2;
        }
    }
#pragma unroll
    for (int s = 0; s < 8; ++s) {
        if (col == s) {
            int jloc = wave * 32 + (s >> 2) * 16 + quad * 4 + (s & 3);
            sidx[jloc] = ci[s];
            float f1 = __uint_as_float(v1[s]), f2 = __uint_as_float(v2[s]);
            if (f2 - f1 < MARGINF) { int pos = atomicAdd(cnt, 1); queue[pos] = n0 + jloc; }
        }
    }
    __syncthreads();

    // epilogue: lane=channel; write loss coalesced; overwrite xs with outq value
    for (int t = 0; t < 32; ++t) {
        int jloc = wave * 32 + t;
        int kidx = sidx[jloc];
        float qv = emb[kidx * DD + lane];              // coalesced 256B row, cache-hot
        float x  = xs[lane][jloc];
        float dv = qv - x;
        float l  = dv * dv;
        outl[(size_t)(n0 + jloc) * DD + lane] = fmaf(0.25f, l, l);   // coalesced
        xs[lane][jloc] = x + (qv - x);                 // in-place: slot owned by this thread
    }
    if (lane < 32) outi[n0 + wave * 32 + lane] = (float)sidx[wave * 32 + lane];
    __syncthreads();
    // coalesced bchw store: lanes sweep hw
#pragma unroll
    for (int it = 0; it < 32; ++it) {
        int f = tid + it * 256;
        int c = f >> 7, j = f & 127;
        outq[((size_t)(b * DD) + c) * HWSZ + hw0 + j] = xs[c][j];
    }
}

// ---- fix: emulate numpy f32 dists grid for queued points, rewrite if changed
// wave per point, lane = channel: coalesced emb rows + f64 butterfly reduce.
__global__ void __launch_bounds__(256)
vq_fix(const float* __restrict__ in, const float* __restrict__ emb,
       const float* __restrict__ se32,
       const int* __restrict__ queue, const int* __restrict__ cnt,
       float* __restrict__ outq, float* __restrict__ outl, float* __restrict__ outi) {
    const int lane = threadIdx.x & 63;
    const int gw   = blockIdx.x * 4 + (threadIdx.x >> 6);
    const int nwav = gridDim.x * 4;
    const int total = *cnt;
    for (int qi = gw; qi < total; qi += nwav) {
        const int n  = queue[qi];
        const int b  = n >> 12, hw = n & 4095;
        const float* inb = in + (size_t)b * DD * HWSZ + hw;
        // numpy-order ||x||^2 via broadcast loads (same addr across lanes)
        float x[DD];
        for (int d = 0; d < DD; ++d) x[d] = inb[d * HWSZ];
        const float sx = np_pairwise64_sq(x);
        // this lane's channel value for the dot
        const double xv = (double)in[((size_t)b * DD + lane) * HWSZ + hw];

        float bD = 3.4e38f; int bi = 0;
        for (int k0 = 0; k0 < KC; k0 += 4) {
            double dot[4];
#pragma unroll
            for (int u = 0; u < 4; ++u)
                dot[u] = xv * (double)emb[(size_t)(k0 + u) * DD + lane];  // coalesced
#pragma unroll
            for (int off = 32; off > 0; off >>= 1) {
#pragma unroll
                for (int u = 0; u < 4; ++u)
                    dot[u] += __shfl_xor(dot[u], off);   // all lanes get full sum
            }
#pragma unroll
            for (int u = 0; u < 4; ++u) {
                float m2 = (float)(2.0 * dot[u]);        // ~= f32 sgemm (single rounding)
                float s1, Dv;
                {
#pragma clang fp contract(off)
                    s1 = sx + se32[k0 + u];
                    Dv = s1 - m2;                        // the reference's f32 grid value
                }
                if (Dv < bD) { bD = Dv; bi = k0 + u; }   // ascending k => first index
            }
        }
        int old = (int)outi[n];
        if (bi != old) {
            float xvf = in[((size_t)b * DD + lane) * HWSZ + hw];
            float qv  = emb[bi * DD + lane];
            float dv  = qv - xvf;
            float l   = dv * dv;
            outl[(size_t)n * DD + lane] = fmaf(0.25f, l, l);
            outq[((size_t)b * DD + lane) * HWSZ + hw] = xvf + (qv - xvf);
            if (lane == 0) outi[n] = (float)bi;
        }
    }
}

extern "C" void kernel_launch(void* const* d_in, const int* in_sizes, int n_in,
                              void* d_out, int out_size, void* d_ws, size_t ws_size,
                              hipStream_t stream) {
    const float* in  = (const float*)d_in[0];   // (32,64,64,64) bchw f32
    const float* emb = (const float*)d_in[1];   // (1024,64) f32

    float* outq = (float*)d_out;                        // 8388608
    float* outl = outq + (size_t)NPTS * DD;             // 8388608
    float* outi = outl + (size_t)NPTS * DD;             // 131072 (idx as f32)

    char*   ws    = (char*)d_ws;                        // ~0.8 MB used
    float*  se32  = (float*)ws;                         // 4 KB
    float*  sebB  = (float*)(ws + 4096);                // 4 KB
    ushort* Ebuf  = (ushort*)(ws + 8192);               // 256 KB (frag-ordered hi/lo)
    int*    cnt   = (int*)(ws + 8192 + 262144);
    int*    queue = (int*)(ws + 8192 + 262144 + 256);   // NPTS*4 worst case

    hipMemsetAsync(cnt, 0, sizeof(int), stream);
    vq_prep_e<<<16, 256, 0, stream>>>(emb, se32, sebB, Ebuf);
    vq_main<<<NPTS / 128, 256, 0, stream>>>(in, emb, Ebuf, sebB, outq, outl, outi, cnt, queue);
    vq_fix<<<512, 256, 0, stream>>>(in, emb, se32, queue, cnt, outq, outl, outi);
}

// Round 6
// 405.378 us; speedup vs baseline: 1.3985x; 1.3985x over previous
//
#include <hip/hip_runtime.h>

#define NPTS    131072     // 32 * 64 * 64 points
#define KC      1024       // codes
#define DD      64         // embedding dim
#define HWSZ    4096       // h*w
#define MARGINF 6e-5f      // packed-domain gap below which we refine on the f32 grid

typedef __attribute__((ext_vector_type(8))) short short8;  // 8 bf16 = 4 VGPRs
typedef __attribute__((ext_vector_type(4))) float f32x4;   // MFMA C/D frag

__device__ __forceinline__ ushort bf16_rne(float x) {
    unsigned u = __float_as_uint(x);
    unsigned r = u + 0x7fffu + ((u >> 16) & 1u);
    return (ushort)(r >> 16);
}

// numpy pairwise sum of a[d]^2, n=64 contiguous path: squares round separately,
// 8 accumulators in numpy's exact order. fp contract OFF (no fma fusion).
__device__ __forceinline__ float np_pairwise64_sq(const float* a) {
#pragma clang fp contract(off)
    float r0 = a[0] * a[0], r1 = a[1] * a[1], r2 = a[2] * a[2], r3 = a[3] * a[3];
    float r4 = a[4] * a[4], r5 = a[5] * a[5], r6 = a[6] * a[6], r7 = a[7] * a[7];
    for (int i = 8; i < 64; i += 8) {
        r0 += a[i + 0] * a[i + 0]; r1 += a[i + 1] * a[i + 1];
        r2 += a[i + 2] * a[i + 2]; r3 += a[i + 3] * a[i + 3];
        r4 += a[i + 4] * a[i + 4]; r5 += a[i + 5] * a[i + 5];
        r6 += a[i + 6] * a[i + 6]; r7 += a[i + 7] * a[i + 7];
    }
    return ((r0 + r1) + (r2 + r3)) + ((r4 + r5) + (r6 + r7));
}

// ---- E prep: ||e||^2 (numpy order), frag-ordered bf16 hi/lo, transposed f32
// Ebuf block (tile,kh,hl): element = E[tile*16+(lane&15)][kh*32+(lane>>4)*8+j]
// embT[d][k] for the fix kernel's coalesced per-d code sweep.
__global__ void __launch_bounds__(256)
vq_prep_e(const float* __restrict__ emb, float* __restrict__ se32,
          float* __restrict__ sebB, ushort* __restrict__ Ebuf,
          float* __restrict__ embT) {
    __shared__ float es_[64][65];
    const int tid = threadIdx.x;
    const int k0  = blockIdx.x * 64;
#pragma unroll
    for (int it = 0; it < 16; ++it) {
        int f = tid + it * 256;
        int kk = f >> 6, d = f & 63;
        es_[kk][d] = emb[(size_t)(k0 + kk) * DD + d];   // coalesced over d
    }
    __syncthreads();
    if (tid < 64) {
        float s = np_pairwise64_sq(&es_[tid][0]);
        se32[k0 + tid] = s;
        sebB[k0 + tid] = s + 0.5f;       // bias keeps scan scores strictly positive
    }
#pragma unroll
    for (int it = 0; it < 16; ++it) {
        int f = tid + it * 256;
        int kk = f >> 6, d = f & 63;
        int k = k0 + kk;
        int tile = k >> 4, colk = k & 15;
        int kh = d >> 5, quad = (d & 31) >> 3, jj = d & 7;
        float ev = es_[kk][d];
        ushort hb = bf16_rne(ev);
        float  hf = __uint_as_float(((unsigned)hb) << 16);
        int pos = (quad * 16 + colk) * 8 + jj;
        Ebuf[((tile * 2 + kh) * 2 + 0) * 512 + pos] = hb;
        Ebuf[((tile * 2 + kh) * 2 + 1) * 512 + pos] = bf16_rne(ev - hf);
    }
    // transposed copy: lanes sweep k -> coalesced writes; LDS read 2-way-free
#pragma unroll
    for (int it = 0; it < 16; ++it) {
        int f  = tid + it * 256;
        int d  = f >> 6, kk = f & 63;
        embT[(size_t)d * KC + k0 + kk] = es_[kk][d];
    }
}

// ---- fused: stage x -> A frags -> MFMA scan (64 pts/wave) -> outputs -------
// A[m][k]: m=lane&15, k=quad*8+j ; C/D: col=lane&15, row=quad*4+reg
__global__ void __launch_bounds__(128, 2)
vq_main(const float* __restrict__ in, const float* __restrict__ emb,
        const ushort* __restrict__ Ebuf, const float* __restrict__ sebB,
        float* __restrict__ outq, float* __restrict__ outl, float* __restrict__ outi,
        int* __restrict__ cnt, int* __restrict__ queue) {
    __shared__ float xs[64][129];   // [c][j] (33 KB); later holds outq values
    __shared__ int   sidx[128];
    const int tid = threadIdx.x;
    const int n0  = blockIdx.x * 128;     // 128 consecutive points, one batch image
    const int b   = n0 >> 12;
    const int hw0 = n0 & 4095;
    const float* inb = in + (size_t)b * DD * HWSZ;

#pragma unroll
    for (int it = 0; it < 64; ++it) {
        int f = tid + it * 128;
        int c = f >> 7, j = f & 127;
        xs[c][j] = inb[c * HWSZ + hw0 + j];   // coalesced over hw
    }
    __syncthreads();

    const int lane = tid & 63, wave = tid >> 6;     // 2 waves, 64 pts each
    const int quad = lane >> 4, col = lane & 15;

    // A fragments (bf16 hi/lo) from LDS: 4 point-subtiles x 2 khalves
    short8 A[4][2][2];
#pragma unroll
    for (int p = 0; p < 4; ++p) {
        int pt = wave * 64 + p * 16 + col;
#pragma unroll
        for (int kh = 0; kh < 2; ++kh) {
            short8 ah, al;
#pragma unroll
            for (int j = 0; j < 8; ++j) {
                float xv = xs[kh * 32 + quad * 8 + j][pt];
                ushort hb = bf16_rne(xv);
                float  hf = __uint_as_float(((unsigned)hb) << 16);
                ah[j] = (short)hb;
                al[j] = (short)bf16_rne(xv - hf);
            }
            A[p][kh][0] = ah; A[p][kh][1] = al;
        }
    }

    unsigned b1[16], b2[16];        // packed: (score+0.5 bits & ~63) | tile
#pragma unroll
    for (int s = 0; s < 16; ++s) { b1[s] = 0xFFFFFFFFu; b2[s] = 0xFFFFFFFFu; }

    for (int g = 0; g < 16; ++g) {            // 64 codes per iteration
#pragma unroll
        for (int s = 0; s < 4; ++s) {
            const int tile = g * 4 + s;
            const float sBs = sebB[tile * 16 + col];
            short8 B[2][2];
#pragma unroll
            for (int kh = 0; kh < 2; ++kh)
#pragma unroll
                for (int hl = 0; hl < 2; ++hl)
                    B[kh][hl] = *(const short8*)(Ebuf + ((tile * 2 + kh) * 2 + hl) * 512 + lane * 8);
            f32x4 acc[4];
#pragma unroll
            for (int p = 0; p < 4; ++p) acc[p] = (f32x4){0.f, 0.f, 0.f, 0.f};
#pragma unroll
            for (int p = 0; p < 4; ++p) {
                acc[p] = __builtin_amdgcn_mfma_f32_16x16x32_bf16(A[p][0][0], B[0][0], acc[p], 0, 0, 0);
                acc[p] = __builtin_amdgcn_mfma_f32_16x16x32_bf16(A[p][1][0], B[1][0], acc[p], 0, 0, 0);
                acc[p] = __builtin_amdgcn_mfma_f32_16x16x32_bf16(A[p][0][0], B[0][1], acc[p], 0, 0, 0);
                acc[p] = __builtin_amdgcn_mfma_f32_16x16x32_bf16(A[p][1][0], B[1][1], acc[p], 0, 0, 0);
                acc[p] = __builtin_amdgcn_mfma_f32_16x16x32_bf16(A[p][0][1], B[0][0], acc[p], 0, 0, 0);
                acc[p] = __builtin_amdgcn_mfma_f32_16x16x32_bf16(A[p][1][1], B[1][0], acc[p], 0, 0, 0);
            }
            // sorted insert, 5 VALU/code: b2 = min(b2, max(b1,q)); b1 = min(b1,q)
#pragma unroll
            for (int p = 0; p < 4; ++p)
#pragma unroll
                for (int r = 0; r < 4; ++r) {
                    float t = fmaf(-2.f, acc[p][r], sBs);      // 0.5 + se - 2x.e > 0
                    unsigned q = (__float_as_uint(t) & 0xFFFFFFC0u) | (unsigned)tile;
                    int sl = p * 4 + r;
                    b2[sl] = min(b2[sl], max(b1[sl], q));
                    b1[sl] = min(b1[sl], q);
                }
        }
    }

    // decode + 16-col butterfly merge (first-index tie-break)
    unsigned v1[16], v2[16]; int ci[16];
#pragma unroll
    for (int s = 0; s < 16; ++s) {
        ci[s] = (int)(b1[s] & 63u) * 16 + col;
        v1[s] = b1[s] & 0xFFFFFFC0u;
        v2[s] = b2[s] & 0xFFFFFFC0u;
    }
#pragma unroll
    for (int off = 1; off < 16; off <<= 1) {
#pragma unroll
        for (int s = 0; s < 16; ++s) {
            unsigned o1 = (unsigned)__shfl_xor((int)v1[s], off);
            unsigned o2 = (unsigned)__shfl_xor((int)v2[s], off);
            int      oi = __shfl_xor(ci[s], off);
            unsigned nb2 = min(min(v2[s], o2), max(v1[s], o1));
            bool take = (o1 < v1[s]) || (o1 == v1[s] && oi < ci[s]);
            v1[s] = take ? o1 : v1[s];
            ci[s] = take ? oi : ci[s];
            v2[s] = nb2;
        }
    }
#pragma unroll
    for (int s = 0; s < 16; ++s) {
        if (col == s) {
            int jloc = wave * 64 + (s >> 2) * 16 + quad * 4 + (s & 3);
            sidx[jloc] = ci[s];
            float f1 = __uint_as_float(v1[s]), f2 = __uint_as_float(v2[s]);
            if (f2 - f1 < MARGINF) { int pos = atomicAdd(cnt, 1); queue[pos] = n0 + jloc; }
        }
    }
    __syncthreads();

    // epilogue: lane=channel; loss coalesced; overwrite xs with outq values
    for (int t = 0; t < 64; ++t) {
        int jloc = wave * 64 + t;
        int kidx = sidx[jloc];
        float qv = emb[kidx * DD + lane];              // coalesced 256B row, cache-hot
        float x  = xs[lane][jloc];
        float dv = qv - x;
        float l  = dv * dv;
        outl[(size_t)(n0 + jloc) * DD + lane] = fmaf(0.25f, l, l);
        xs[lane][jloc] = x + (qv - x);                 // slot owned by this thread
    }
    outi[n0 + tid] = (float)sidx[tid];
    __syncthreads();
#pragma unroll
    for (int it = 0; it < 64; ++it) {                  // coalesced bchw store
        int f = tid + it * 128;
        int c = f >> 7, j = f & 127;
        outq[((size_t)(b * DD) + c) * HWSZ + hw0 + j] = xs[c][j];
    }
}

// ---- fix: emulate numpy f32 dists grid for queued points -------------------
// block per point; lane = code (4 codes/lane); coalesced embT[d][k] sweeps.
__global__ void __launch_bounds__(256)
vq_fix(const float* __restrict__ in, const float* __restrict__ emb,
       const float* __restrict__ embT, const float* __restrict__ se32,
       const int* __restrict__ queue, const int* __restrict__ cnt,
       float* __restrict__ outq, float* __restrict__ outl, float* __restrict__ outi) {
    __shared__ float rv[4];
    __shared__ int   ri[4];
    __shared__ int   bk;
    const int tid  = threadIdx.x;
    const int lane = tid & 63, wave = tid >> 6;
    const int total = *cnt;
    for (int qi = blockIdx.x; qi < total; qi += gridDim.x) {
        const int n  = queue[qi];
        const int b  = n >> 12, hw = n & 4095;
        const float* inb = in + (size_t)b * DD * HWSZ + hw;
        // x is block-uniform: broadcast loads
        float x[DD];
#pragma unroll
        for (int d = 0; d < DD; ++d) x[d] = inb[d * HWSZ];
        const float sx = np_pairwise64_sq(x);          // numpy-order ||x||^2

        const int kb = wave * 256 + lane;              // this lane's 4 codes: kb + u*64
        double a0 = 0.0, a1 = 0.0, a2 = 0.0, a3 = 0.0;
#pragma unroll
        for (int d = 0; d < DD; ++d) {
            const float* row = embT + (size_t)d * KC + kb;
            double xd = (double)x[d];
            a0 = fma(xd, (double)row[0],   a0);        // coalesced over lanes
            a1 = fma(xd, (double)row[64],  a1);
            a2 = fma(xd, (double)row[128], a2);
            a3 = fma(xd, (double)row[192], a3);
        }
        double dots[4] = {a0, a1, a2, a3};
        float bD = 3.4e38f; int bi = 0x7fffffff;
#pragma unroll
        for (int u = 0; u < 4; ++u) {
            float m2 = (float)(2.0 * dots[u]);         // ~= f32 sgemm, single rounding
            float s1, Dv;
            {
#pragma clang fp contract(off)
                s1 = sx + se32[kb + u * 64];
                Dv = s1 - m2;                          // the reference's f32 grid value
            }
            if (Dv < bD) { bD = Dv; bi = kb + u * 64; }   // ascending k per lane
        }
        // wave argmin (value, index) lexicographic
#pragma unroll
        for (int off = 32; off > 0; off >>= 1) {
            float oD = __shfl_xor(bD, off);
            int   oi = __shfl_xor(bi, off);
            if (oD < bD || (oD == bD && oi < bi)) { bD = oD; bi = oi; }
        }
        if (lane == 0) { rv[wave] = bD; ri[wave] = bi; }
        __syncthreads();
        if (tid == 0) {
            float fD = rv[0]; int fi = ri[0];
#pragma unroll
            for (int w = 1; w < 4; ++w)
                if (rv[w] < fD || (rv[w] == fD && ri[w] < fi)) { fD = rv[w]; fi = ri[w]; }
            bk = fi;
        }
        __syncthreads();
        const int bestK = bk;
        const int old   = (int)outi[n];
        if (bestK != old && tid < 64) {
            float xvf = in[((size_t)b * DD + lane) * HWSZ + hw];
            float qv  = emb[bestK * DD + lane];
            float dv  = qv - xvf;
            float l   = dv * dv;
            outl[(size_t)n * DD + lane] = fmaf(0.25f, l, l);
            outq[((size_t)b * DD + lane) * HWSZ + hw] = xvf + (qv - xvf);
            if (lane == 0) outi[n] = (float)bestK;
        }
        __syncthreads();
    }
}

extern "C" void kernel_launch(void* const* d_in, const int* in_sizes, int n_in,
                              void* d_out, int out_size, void* d_ws, size_t ws_size,
                              hipStream_t stream) {
    const float* in  = (const float*)d_in[0];   // (32,64,64,64) bchw f32
    const float* emb = (const float*)d_in[1];   // (1024,64) f32

    float* outq = (float*)d_out;                        // 8388608
    float* outl = outq + (size_t)NPTS * DD;             // 8388608
    float* outi = outl + (size_t)NPTS * DD;             // 131072 (idx as f32)

    char*   ws    = (char*)d_ws;                        // ~1.05 MB used
    float*  se32  = (float*)ws;                         // 4 KB
    float*  sebB  = (float*)(ws + 4096);                // 4 KB
    ushort* Ebuf  = (ushort*)(ws + 8192);               // 256 KB (frag-ordered hi/lo)
    float*  embT  = (float*)(ws + 8192 + 262144);       // 256 KB ([d][k] f32)
    int*    cnt   = (int*)(ws + 8192 + 262144 + 262144);
    int*    queue = (int*)(ws + 8192 + 262144 + 262144 + 256);   // NPTS*4 worst case

    hipMemsetAsync(cnt, 0, sizeof(int), stream);
    vq_prep_e<<<16, 256, 0, stream>>>(emb, se32, sebB, Ebuf, embT);
    vq_main<<<NPTS / 128, 128, 0, stream>>>(in, emb, Ebuf, sebB, outq, outl, outi, cnt, queue);
    vq_fix<<<2048, 256, 0, stream>>>(in, emb, embT, se32, queue, cnt, outq, outl, outi);
}

// Round 7
// 291.703 us; speedup vs baseline: 1.9435x; 1.3897x over previous
//
#include <hip/hip_runtime.h>

#define NPTS    131072     // 32 * 64 * 64 points
#define KC      1024       // codes
#define DD      64         // embedding dim
#define HWSZ    4096       // h*w
#define MARGINF 6e-5f      // packed-domain gap below which we refine on the f32 grid

typedef __attribute__((ext_vector_type(8))) short short8;  // 8 bf16 = 4 VGPRs
typedef __attribute__((ext_vector_type(4))) float f32x4;   // MFMA C/D frag

__device__ __forceinline__ ushort bf16_rne(float x) {
    unsigned u = __float_as_uint(x);
    unsigned r = u + 0x7fffu + ((u >> 16) & 1u);
    return (ushort)(r >> 16);
}

// numpy pairwise sum of a[d]^2, n=64 contiguous path: squares round separately,
// 8 accumulators in numpy's exact order. fp contract OFF (no fma fusion).
// Works on an LDS pointer: only 8 live accumulators -> no spill.
__device__ __forceinline__ float np_pairwise64_sq(const float* a) {
#pragma clang fp contract(off)
    float r0 = a[0] * a[0], r1 = a[1] * a[1], r2 = a[2] * a[2], r3 = a[3] * a[3];
    float r4 = a[4] * a[4], r5 = a[5] * a[5], r6 = a[6] * a[6], r7 = a[7] * a[7];
    for (int i = 8; i < 64; i += 8) {
        r0 += a[i + 0] * a[i + 0]; r1 += a[i + 1] * a[i + 1];
        r2 += a[i + 2] * a[i + 2]; r3 += a[i + 3] * a[i + 3];
        r4 += a[i + 4] * a[i + 4]; r5 += a[i + 5] * a[i + 5];
        r6 += a[i + 6] * a[i + 6]; r7 += a[i + 7] * a[i + 7];
    }
    return ((r0 + r1) + (r2 + r3)) + ((r4 + r5) + (r6 + r7));
}

// ---- E prep: ||e||^2 (numpy order), frag-ordered bf16 hi/lo, transposed f32
__global__ void __launch_bounds__(256)
vq_prep_e(const float* __restrict__ emb, float* __restrict__ se32,
          float* __restrict__ sebB, ushort* __restrict__ Ebuf,
          float* __restrict__ embT) {
    __shared__ float es_[64][65];
    const int tid = threadIdx.x;
    const int k0  = blockIdx.x * 64;
#pragma unroll
    for (int it = 0; it < 16; ++it) {
        int f = tid + it * 256;
        int kk = f >> 6, d = f & 63;
        es_[kk][d] = emb[(size_t)(k0 + kk) * DD + d];   // coalesced over d
    }
    __syncthreads();
    if (tid < 64) {
        float s = np_pairwise64_sq(&es_[tid][0]);
        se32[k0 + tid] = s;
        sebB[k0 + tid] = s + 0.5f;       // bias keeps scan scores strictly positive
    }
#pragma unroll
    for (int it = 0; it < 16; ++it) {
        int f = tid + it * 256;
        int kk = f >> 6, d = f & 63;
        int k = k0 + kk;
        int tile = k >> 4, colk = k & 15;
        int kh = d >> 5, quad = (d & 31) >> 3, jj = d & 7;
        float ev = es_[kk][d];
        ushort hb = bf16_rne(ev);
        float  hf = __uint_as_float(((unsigned)hb) << 16);
        int pos = (quad * 16 + colk) * 8 + jj;
        Ebuf[((tile * 2 + kh) * 2 + 0) * 512 + pos] = hb;
        Ebuf[((tile * 2 + kh) * 2 + 1) * 512 + pos] = bf16_rne(ev - hf);
    }
    // transposed copy for vq_fix: lanes sweep k -> coalesced writes
#pragma unroll
    for (int it = 0; it < 16; ++it) {
        int f  = tid + it * 256;
        int d  = f >> 6, kk = f & 63;
        embT[(size_t)d * KC + k0 + kk] = es_[kk][d];
    }
}

// ---- fused: stage x -> A frags -> MFMA scan (packed-uint argmin) -> outputs
// (R5 structure: 256 threads, 4 waves x 32 points, 8 acc slots)
__global__ void __launch_bounds__(256)
vq_main(const float* __restrict__ in, const float* __restrict__ emb,
        const ushort* __restrict__ Ebuf, const float* __restrict__ sebB,
        float* __restrict__ outq, float* __restrict__ outl, float* __restrict__ outi,
        int* __restrict__ cnt, int* __restrict__ queue) {
    __shared__ float xs[64][129];   // [c][j] (33 KB); later holds outq values
    __shared__ int   sidx[128];
    const int tid = threadIdx.x;
    const int n0  = blockIdx.x * 128;     // 128 consecutive points, one batch image
    const int b   = n0 >> 12;
    const int hw0 = n0 & 4095;
    const float* inb = in + (size_t)b * DD * HWSZ;

#pragma unroll
    for (int it = 0; it < 32; ++it) {
        int f = tid + it * 256;
        int c = f >> 7, j = f & 127;
        xs[c][j] = inb[c * HWSZ + hw0 + j];   // coalesced over hw
    }
    __syncthreads();

    const int lane = tid & 63, wave = tid >> 6;
    const int quad = lane >> 4, col = lane & 15;

    // A fragments (bf16 hi/lo) from LDS
    short8 A[2][2][2];   // [psub][khalf][hi/lo]
#pragma unroll
    for (int p = 0; p < 2; ++p) {
        int pt = wave * 32 + p * 16 + col;
#pragma unroll
        for (int kh = 0; kh < 2; ++kh) {
            short8 ah, al;
#pragma unroll
            for (int j = 0; j < 8; ++j) {
                float xv = xs[kh * 32 + quad * 8 + j][pt];
                ushort hb = bf16_rne(xv);
                float  hf = __uint_as_float(((unsigned)hb) << 16);
                ah[j] = (short)hb;
                al[j] = (short)bf16_rne(xv - hf);
            }
            A[p][kh][0] = ah; A[p][kh][1] = al;
        }
    }

    unsigned b1[8], b2[8];          // packed: (score+0.5 bits & ~63) | tile
#pragma unroll
    for (int s = 0; s < 8; ++s) { b1[s] = 0xFFFFFFFFu; b2[s] = 0xFFFFFFFFu; }

    for (int g = 0; g < 16; ++g) {            // 64 codes per iteration
        short8 B[4][2][2];
        float  sB[4];
#pragma unroll
        for (int s = 0; s < 4; ++s) {
            int tile = g * 4 + s;
            sB[s] = sebB[tile * 16 + col];
#pragma unroll
            for (int kh = 0; kh < 2; ++kh)
#pragma unroll
                for (int hl = 0; hl < 2; ++hl)
                    B[s][kh][hl] = *(const short8*)(Ebuf + ((tile * 2 + kh) * 2 + hl) * 512 + lane * 8);
        }
        f32x4 acc[2][4];
#pragma unroll
        for (int p = 0; p < 2; ++p)
#pragma unroll
            for (int s = 0; s < 4; ++s) acc[p][s] = (f32x4){0.f, 0.f, 0.f, 0.f};
#pragma unroll
        for (int p = 0; p < 2; ++p)
#pragma unroll
            for (int s = 0; s < 4; ++s) {
                acc[p][s] = __builtin_amdgcn_mfma_f32_16x16x32_bf16(A[p][0][0], B[s][0][0], acc[p][s], 0, 0, 0);
                acc[p][s] = __builtin_amdgcn_mfma_f32_16x16x32_bf16(A[p][1][0], B[s][1][0], acc[p][s], 0, 0, 0);
                acc[p][s] = __builtin_amdgcn_mfma_f32_16x16x32_bf16(A[p][0][0], B[s][0][1], acc[p][s], 0, 0, 0);
                acc[p][s] = __builtin_amdgcn_mfma_f32_16x16x32_bf16(A[p][1][0], B[s][1][1], acc[p][s], 0, 0, 0);
                acc[p][s] = __builtin_amdgcn_mfma_f32_16x16x32_bf16(A[p][0][1], B[s][0][0], acc[p][s], 0, 0, 0);
                acc[p][s] = __builtin_amdgcn_mfma_f32_16x16x32_bf16(A[p][1][1], B[s][1][0], acc[p][s], 0, 0, 0);
            }
        // packed-uint fold: 4 codes per slot via sorted-2-of-4 insertion
#pragma unroll
        for (int p = 0; p < 2; ++p)
#pragma unroll
            for (int r = 0; r < 4; ++r) {
                unsigned q[4];
#pragma unroll
                for (int s = 0; s < 4; ++s) {
                    float t = fmaf(-2.f, acc[p][s][r], sB[s]);       // 0.5 + se - 2x.e > 0
                    q[s] = (__float_as_uint(t) & 0xFFFFFFC0u) | (unsigned)(g * 4 + s);
                }
                unsigned a  = min(q[0], q[1]), bb = max(q[0], q[1]);
                unsigned c2 = min(q[2], q[3]), d2 = max(q[2], q[3]);
                unsigned lo = min(a, c2), hi = max(a, c2);
                unsigned sec = min(min(bb, d2), hi);                  // 2nd smallest of 4
                int sl = p * 4 + r;
                b2[sl] = min(min(b2[sl], sec), max(b1[sl], lo));
                b1[sl] = min(b1[sl], lo);
            }
    }

    // decode + 16-col butterfly merge (first-index tie-break)
    unsigned v1[8], v2[8]; int ci[8];
#pragma unroll
    for (int s = 0; s < 8; ++s) {
        ci[s] = (int)(b1[s] & 63u) * 16 + col;
        v1[s] = b1[s] & 0xFFFFFFC0u;
        v2[s] = b2[s] & 0xFFFFFFC0u;
    }
#pragma unroll
    for (int off = 1; off < 16; off <<= 1) {
#pragma unroll
        for (int s = 0; s < 8; ++s) {
            unsigned o1 = (unsigned)__shfl_xor((int)v1[s], off);
            unsigned o2 = (unsigned)__shfl_xor((int)v2[s], off);
            int      oi = __shfl_xor(ci[s], off);
            unsigned nb2 = min(min(v2[s], o2), max(v1[s], o1));
            bool take = (o1 < v1[s]) || (o1 == v1[s] && oi < ci[s]);
            v1[s] = take ? o1 : v1[s];
            ci[s] = take ? oi : ci[s];
            v2[s] = nb2;
        }
    }
#pragma unroll
    for (int s = 0; s < 8; ++s) {
        if (col == s) {
            int jloc = wave * 32 + (s >> 2) * 16 + quad * 4 + (s & 3);
            sidx[jloc] = ci[s];
            float f1 = __uint_as_float(v1[s]), f2 = __uint_as_float(v2[s]);
            if (f2 - f1 < MARGINF) { int pos = atomicAdd(cnt, 1); queue[pos] = n0 + jloc; }
        }
    }
    __syncthreads();

    // epilogue: lane=channel; loss coalesced; overwrite xs with outq values
    for (int t = 0; t < 32; ++t) {
        int jloc = wave * 32 + t;
        int kidx = sidx[jloc];
        float qv = emb[kidx * DD + lane];              // coalesced 256B row, cache-hot
        float x  = xs[lane][jloc];
        float dv = qv - x;
        float l  = dv * dv;
        outl[(size_t)(n0 + jloc) * DD + lane] = fmaf(0.25f, l, l);
        xs[lane][jloc] = x + (qv - x);                 // slot owned by this thread
    }
    if (lane < 32) outi[n0 + wave * 32 + lane] = (float)sidx[wave * 32 + lane];
    __syncthreads();
#pragma unroll
    for (int it = 0; it < 32; ++it) {                  // coalesced bchw store
        int f = tid + it * 256;
        int c = f >> 7, j = f & 127;
        outq[((size_t)(b * DD) + c) * HWSZ + hw0 + j] = xs[c][j];
    }
}

// ---- fix: emulate numpy f32 dists grid for queued points -------------------
// block per point; x staged in LDS (block-uniform -> NO per-thread array/spill);
// lane = code (4 codes/lane) over coalesced embT[d][k] sweeps.
__global__ void __launch_bounds__(256)
vq_fix(const float* __restrict__ in, const float* __restrict__ emb,
       const float* __restrict__ embT, const float* __restrict__ se32,
       const int* __restrict__ queue, const int* __restrict__ cnt,
       float* __restrict__ outq, float* __restrict__ outl, float* __restrict__ outi) {
    __shared__ float xlds[64];
    __shared__ float rv[4];
    __shared__ int   ri[4];
    __shared__ int   bk;
    const int tid  = threadIdx.x;
    const int lane = tid & 63, wave = tid >> 6;
    const int total = *cnt;
    for (int qi = blockIdx.x; qi < total; qi += gridDim.x) {
        const int n  = queue[qi];
        const int b  = n >> 12, hw = n & 4095;
        if (tid < 64) xlds[tid] = in[((size_t)b * DD + tid) * HWSZ + hw];
        __syncthreads();
        const float sx = np_pairwise64_sq(xlds);       // LDS broadcast reads, 8 accs

        const int kb = wave * 256 + lane;              // this lane's 4 codes: kb + u*64
        double a0 = 0.0, a1 = 0.0, a2 = 0.0, a3 = 0.0;
#pragma unroll 8
        for (int d = 0; d < DD; ++d) {
            const float* row = embT + (size_t)d * KC + kb;
            double xd = (double)xlds[d];
            a0 = fma(xd, (double)row[0],   a0);        // coalesced over lanes
            a1 = fma(xd, (double)row[64],  a1);
            a2 = fma(xd, (double)row[128], a2);
            a3 = fma(xd, (double)row[192], a3);
        }
        double dots[4] = {a0, a1, a2, a3};
        float bD = 3.4e38f; int bi = 0x7fffffff;
#pragma unroll
        for (int u = 0; u < 4; ++u) {
            float m2 = (float)(2.0 * dots[u]);         // ~= f32 sgemm, single rounding
            float s1, Dv;
            {
#pragma clang fp contract(off)
                s1 = sx + se32[kb + u * 64];
                Dv = s1 - m2;                          // the reference's f32 grid value
            }
            if (Dv < bD) { bD = Dv; bi = kb + u * 64; }   // ascending k per lane
        }
        // wave argmin (value, index) lexicographic
#pragma unroll
        for (int off = 32; off > 0; off >>= 1) {
            float oD = __shfl_xor(bD, off);
            int   oi = __shfl_xor(bi, off);
            if (oD < bD || (oD == bD && oi < bi)) { bD = oD; bi = oi; }
        }
        if (lane == 0) { rv[wave] = bD; ri[wave] = bi; }
        __syncthreads();
        if (tid == 0) {
            float fD = rv[0]; int fi = ri[0];
#pragma unroll
            for (int w = 1; w < 4; ++w)
                if (rv[w] < fD || (rv[w] == fD && ri[w] < fi)) { fD = rv[w]; fi = ri[w]; }
            bk = fi;
        }
        __syncthreads();
        const int bestK = bk;
        const int old   = (int)outi[n];
        if (bestK != old && tid < 64) {
            float xvf = xlds[lane];
            float qv  = emb[bestK * DD + lane];
            float dv  = qv - xvf;
            float l   = dv * dv;
            outl[(size_t)n * DD + lane] = fmaf(0.25f, l, l);
            outq[((size_t)b * DD + lane) * HWSZ + hw] = xvf + (qv - xvf);
            if (lane == 0) outi[n] = (float)bestK;
        }
        __syncthreads();   // xlds/rv/ri reused next iteration
    }
}

extern "C" void kernel_launch(void* const* d_in, const int* in_sizes, int n_in,
                              void* d_out, int out_size, void* d_ws, size_t ws_size,
                              hipStream_t stream) {
    const float* in  = (const float*)d_in[0];   // (32,64,64,64) bchw f32
    const float* emb = (const float*)d_in[1];   // (1024,64) f32

    float* outq = (float*)d_out;                        // 8388608
    float* outl = outq + (size_t)NPTS * DD;             // 8388608
    float* outi = outl + (size_t)NPTS * DD;             // 131072 (idx as f32)

    char*   ws    = (char*)d_ws;                        // ~1.05 MB used
    float*  se32  = (float*)ws;                         // 4 KB
    float*  sebB  = (float*)(ws + 4096);                // 4 KB
    ushort* Ebuf  = (ushort*)(ws + 8192);               // 256 KB (frag-ordered hi/lo)
    float*  embT  = (float*)(ws + 8192 + 262144);       // 256 KB ([d][k] f32)
    int*    cnt   = (int*)(ws + 8192 + 262144 + 262144);
    int*    queue = (int*)(ws + 8192 + 262144 + 262144 + 256);   // NPTS*4 worst case

    hipMemsetAsync(cnt, 0, sizeof(int), stream);
    vq_prep_e<<<16, 256, 0, stream>>>(emb, se32, sebB, Ebuf, embT);
    vq_main<<<NPTS / 128, 256, 0, stream>>>(in, emb, Ebuf, sebB, outq, outl, outi, cnt, queue);
    vq_fix<<<2048, 256, 0, stream>>>(in, emb, embT, se32, queue, cnt, outq, outl, outi);
}